// Round 21
// baseline (3786.707 us; speedup 1.0000x reference)
//
#include <hip/hip_runtime.h>

#define Bb 64
#define Ss 512
#define Ff 512
#define Hh 512
#define GW 2048  // 4H
#define NWGD 128 // workgroups per direction (4 h-cols each)
#define FLAG_STRIDE 4   // u32 stride between flags = 16B

using bf16x8 = __attribute__((ext_vector_type(8))) short;
using f32x4  = __attribute__((ext_vector_type(4))) float;
typedef __attribute__((ext_vector_type(4))) short short4v;
typedef unsigned short u16;
typedef unsigned long long u64;

__device__ __forceinline__ short f2bf(float f) {
  unsigned u = __builtin_bit_cast(unsigned, f);
  u = (u + 0x7FFFu + ((u >> 16) & 1u)) >> 16;
  return (short)u;
}
__device__ __forceinline__ float fsigmoid(float x) {
  return 1.f / (1.f + __expf(-x));
}
__device__ __forceinline__ float ftanh(float x) {
  x = fminf(fmaxf(x, -15.f), 15.f);
  float e = __expf(-2.f * x);
  return (1.f - e) / (1.f + e);
}

// ws layout:
//   [0, 262144)          : h double buffer  [2][2dirs][64][512] bf16
//   [262144, +4096)      : arrival flags, [2 dirs][128 WGs], 16B apart
//   [278528, +33554432)  : optional x as bf16 [64][512][512]
#define HBUF_ELEMS (2 * Bb * Hh)
#define BAR_OFF    262144
#define XB_OFF     (262144 + 16384)
#define NFLAGW     (2 * NWGD * FLAG_STRIDE)

__global__ void init_kernel(const float* __restrict__ x, u16* hbuf0,
                            unsigned* flags, u16* xb, int do_conv) {
  const int gtid = blockIdx.x * blockDim.x + threadIdx.x;
  const int gstride = gridDim.x * blockDim.x;
  for (int i = gtid; i < NFLAGW; i += gstride) flags[i] = 0u;
  for (int i = gtid; i < HBUF_ELEMS; i += gstride) hbuf0[i] = 0;
  if (do_conv) {
    const float4* xv = (const float4*)x;
    const int n4 = Bb * Ss * Ff / 4;
    for (int i = gtid; i < n4; i += gstride) {
      float4 v = xv[i];
      short4v o;
      o[0] = f2bf(v.x); o[1] = f2bf(v.y); o[2] = f2bf(v.z); o[3] = f2bf(v.w);
      ((short4v*)xb)[i] = o;
    }
  }
}

template <int XPRE>
__global__ void __launch_bounds__(256, 2)
bilstm_kernel(const float* __restrict__ x, const u16* __restrict__ xb,
              const float* __restrict__ Wf, const float* __restrict__ Uf,
              const float* __restrict__ bfp, const float* __restrict__ Wb,
              const float* __restrict__ Ub, const float* __restrict__ bbp,
              float* __restrict__ out, u16* __restrict__ hbuf,
              unsigned* __restrict__ barflags) {
  const int tid = threadIdx.x, wg = blockIdx.x;
  const int dir = wg & 1;        // interleaved so each dir spans XCDs evenly
  const int blk = wg >> 1;       // 0..127, owns h-cols [blk*4, blk*4+4)
  const int wid = tid >> 6, lane = tid & 63;
  const int n = lane & 15, kgrp = lane >> 4;

  __shared__ unsigned scnt;      // monotone per-WG arrive counter
  if (tid == 0) scnt = 0u;
  __syncthreads();

  const float* W    = dir ? Wb : Wf;
  const float* Uu   = dir ? Ub : Uf;
  const float* bias = dir ? bbp : bfp;

  // one 16-col B-tile: col n -> gate g = n>>2, h-col = blk*4 + (n&3)
  const int gc = (n >> 2) * Hh + blk * 4 + (n & 3);
  const float b_own = bias[gc];

  // ---- weight fragments in registers (once): 16 k-slices each ----
  bf16x8 wfW[16], wfU[16];
#pragma unroll
  for (int ks = 0; ks < 16; ++ks) {
    bf16x8 w0, u0;
#pragma unroll
    for (int j = 0; j < 8; ++j) {
      const int k = ks * 32 + kgrp * 8 + j;
      w0[j] = f2bf(W[(size_t)k * GW + gc]);
      u0[j] = f2bf(Uu[(size_t)k * GW + gc]);
    }
    wfW[ks] = w0;
    wfU[ks] = u0;
  }

  const int arow = wid * 16 + n;  // batch row for A-fragments
  float c_reg[4] = {0.f, 0.f, 0.f, 0.f};

  u16* hb0 = hbuf;
  u16* hb1 = hbuf + HBUF_ELEMS;
  unsigned* flags  = barflags + (size_t)dir * NWGD * FLAG_STRIDE;
  unsigned* myflag = flags + (size_t)blk * FLAG_STRIDE;
  // per-lane poll slot: chunk c covers producers [32c, 32c+32)
  const unsigned* fpl = flags + (size_t)(lane & 31) * FLAG_STRIDE;

  float* out_hidden = out;
  float* out_h = out + (size_t)Bb * Ss * 2 * Hh;
  float* out_c = out_h + (size_t)Bb * 2 * Hh;

  bf16x8 afx[16];
  f32x4 accX;

  auto issue_x = [&](int t) {
    if (XPRE) {
      const u16* xbase = xb + ((size_t)arow * Ss + t) * Ff + kgrp * 8;
#pragma unroll
      for (int ks = 0; ks < 16; ++ks)
        afx[ks] = *(const bf16x8*)(xbase + ks * 32);
    }
  };
  auto finish_x = [&](int t) {
    f32x4 t0 = {0.f, 0.f, 0.f, 0.f};
    const float* xrow = x + ((size_t)arow * Ss + t) * Ff + kgrp * 8;
#pragma unroll
    for (int ks = 0; ks < 16; ++ks) {
      bf16x8 a;
      if (XPRE) {
        a = afx[ks];
      } else {
        const f32x4 p0 = *(const f32x4*)(xrow + ks * 32);
        const f32x4 p1 = *(const f32x4*)(xrow + ks * 32 + 4);
#pragma unroll
        for (int j = 0; j < 4; ++j) {
          a[j] = f2bf(p0[j]);
          a[j + 4] = f2bf(p1[j]);
        }
      }
      t0 = __builtin_amdgcn_mfma_f32_16x16x32_bf16(a, wfW[ks], t0, 0, 0, 0);
    }
    accX = t0;
  };

  // prologue: x-part for step 0
  {
    const int t0i = dir ? (Ss - 1) : 0;
    issue_x(t0i);
    finish_x(t0i);
  }

  for (int s = 0; s < Ss; ++s) {
    u16* hcur = (s & 1) ? hb1 : hb0;
    u16* hnxt = (s & 1) ? hb0 : hb1;
    const bool last = (s == Ss - 1);

    // ---- chunked per-wave poll + h loads (R19-proven): chunk c gates on
    //      producers [32c,32c+32), then issues those 4 sc-bypass loads.
    //      Straggler wait overlaps earlier chunks' load RT. ----
    const u16* hbase = hcur + (size_t)dir * Bb * Hh + (size_t)arow * Hh + kgrp * 8;
    bf16x8 ah[16];
    const unsigned tgt = (unsigned)s;
#pragma unroll
    for (int c = 0; c < 4; ++c) {
      if (s > 0) {
        const unsigned* fp = fpl + (size_t)(c * 32) * FLAG_STRIDE;
        for (;;) {
          const unsigned a = __hip_atomic_load(fp, __ATOMIC_RELAXED,
                                               __HIP_MEMORY_SCOPE_AGENT);
          if (__all(a >= tgt)) break;
          __builtin_amdgcn_s_sleep(1);
        }
        __builtin_amdgcn_sched_barrier(0);
      }
#pragma unroll
      for (int k2 = 0; k2 < 4; ++k2) {
        const int ks = c * 4 + k2;
        asm volatile("global_load_dwordx4 %0, %1, off offset:%c2 sc0 sc1"
                     : "=v"(ah[ks])
                     : "v"(hbase), "i"(ks * 64)
                     : "memory");
      }
    }

    // ---- split-wait h@U: chunks 0-2 are resident once <=4 ops remain
    //      (vmcnt retires in issue order); their 12 MFMAs overlap chunk-3 RT ----
    f32x4 accA = accX;
    f32x4 accB = {0.f, 0.f, 0.f, 0.f};
    asm volatile("s_waitcnt vmcnt(4)" ::: "memory");
    __builtin_amdgcn_sched_barrier(0);
#pragma unroll
    for (int ks = 0; ks < 6; ++ks) {
      accA = __builtin_amdgcn_mfma_f32_16x16x32_bf16(ah[2 * ks], wfU[2 * ks], accA, 0, 0, 0);
      accB = __builtin_amdgcn_mfma_f32_16x16x32_bf16(ah[2 * ks + 1], wfU[2 * ks + 1], accB, 0, 0, 0);
    }
    asm volatile("s_waitcnt vmcnt(0)" ::: "memory");
    __builtin_amdgcn_sched_barrier(0);
#pragma unroll
    for (int ks = 6; ks < 8; ++ks) {
      accA = __builtin_amdgcn_mfma_f32_16x16x32_bf16(ah[2 * ks], wfU[2 * ks], accA, 0, 0, 0);
      accB = __builtin_amdgcn_mfma_f32_16x16x32_bf16(ah[2 * ks + 1], wfU[2 * ks + 1], accB, 0, 0, 0);
    }
    f32x4 acc;
#pragma unroll
    for (int r = 0; r < 4; ++r) acc[r] = accA[r] + accB[r];

    const int tnext = dir ? (Ss - 2 - s) : (s + 1);
    if (!last) issue_x(tnext);  // loads in flight under combine

    // ---- wave-local gate combine (valid in lanes n<4) ----
    float hv[4];
#pragma unroll
    for (int r = 0; r < 4; ++r) {
      const float a = acc[r] + b_own;
      const float act = ((n >> 2) == 2) ? ftanh(a) : fsigmoid(a);
      const float f4  = __shfl_xor(act, 4);   // lane n<4: forget gate
      const float g8  = __shfl_xor(act, 8);   // lane n<4: cell gate
      const float o12 = __shfl_xor(act, 12);  // lane n<4: output gate
      c_reg[r] = f4 * c_reg[r] + act * g8;
      hv[r] = o12 * ftanh(c_reg[r]);
    }
    float hnb[4];
#pragma unroll
    for (int r = 0; r < 4; ++r) hnb[r] = __shfl_xor(hv[r], 1);
    float cnb[4];
    if (last) {
#pragma unroll
      for (int r = 0; r < 4; ++r) cnb[r] = __shfl_xor(c_reg[r], 1);
    }

    const bool owner = ((n & 1) == 0 && n < 4);  // lanes n in {0,2}
    const int col = blk * 4 + n;

    // ---- h store ONLY before the arrive ----
    if (owner) {
#pragma unroll
      for (int r = 0; r < 4; ++r) {
        const int row = wid * 16 + kgrp * 4 + r;
        const unsigned hp = (unsigned)(unsigned short)f2bf(hv[r]) |
                            ((unsigned)(unsigned short)f2bf(hnb[r]) << 16);
        // write-through (agent scope); drained by this wave's vmcnt(0) below
        __hip_atomic_store(
            (unsigned*)(hnxt + (size_t)dir * Bb * Hh + (size_t)row * Hh + col),
            hp, __ATOMIC_RELAXED, __HIP_MEMORY_SCOPE_AGENT);
      }
    }

    // ---- LDS-atomic arrive (no syncthreads): each wave drains its own
    //      stores; the 4th wave to arrive stores the flag. Adds are strictly
    //      step-ordered (a wave can't pass step-s's poll until all step-(s-1)
    //      adds happened), so old == 4s+3 identifies the last arrival. ----
    if (!last) {
      asm volatile("s_waitcnt vmcnt(0)" ::: "memory");
      __builtin_amdgcn_sched_barrier(0);
      if (lane == 0) {
        const unsigned old = atomicAdd(&scnt, 1u);
        if (old == 4u * (unsigned)s + 3u)
          __hip_atomic_store(myflag, (unsigned)(s + 1), __ATOMIC_RELAXED,
                             __HIP_MEMORY_SCOPE_AGENT);
      }
    }

    // ---- out stores after the arrive (R19-proven placement) ----
    if (owner) {
#pragma unroll
      for (int r = 0; r < 4; ++r) {
        const int row = wid * 16 + kgrp * 4 + r;
        float2 o2;
        o2.x = hv[r]; o2.y = hnb[r];
        __hip_atomic_store(
            (u64*)(out_hidden + (size_t)row * Ss * 2 * Hh + (size_t)s * 2 * Hh +
                   (size_t)dir * Hh + col),
            __builtin_bit_cast(u64, o2), __ATOMIC_RELAXED,
            __HIP_MEMORY_SCOPE_AGENT);
        if (last) {  // end-of-kernel writeback handles visibility for these
          *(float2*)(out_h + (size_t)row * 2 * Hh + (size_t)dir * Hh + col) = o2;
          if (dir == 0) {  // bug-faithful: c_t = [c_fwd, c_fwd]
            float2 c2;
            c2.x = c_reg[r]; c2.y = cnb[r];
            *(float2*)(out_c + (size_t)row * 2 * Hh + col) = c2;
            *(float2*)(out_c + (size_t)row * 2 * Hh + Hh + col) = c2;
          }
        }
      }
    }

    // ---- x@W for the next step (register MFMAs, overlaps flag propagation) ----
    if (!last) finish_x(tnext);
  }
}

extern "C" void kernel_launch(void* const* d_in, const int* in_sizes, int n_in,
                              void* d_out, int out_size, void* d_ws, size_t ws_size,
                              hipStream_t stream) {
  const float* x  = (const float*)d_in[0];
  const float* Wf = (const float*)d_in[1];
  const float* Uf = (const float*)d_in[2];
  const float* bf = (const float*)d_in[3];
  const float* Wb = (const float*)d_in[4];
  const float* Ub = (const float*)d_in[5];
  const float* bb = (const float*)d_in[6];
  float* out = (float*)d_out;

  u16* hbuf       = (u16*)d_ws;
  unsigned* flags = (unsigned*)((char*)d_ws + BAR_OFF);
  u16* xb         = (u16*)((char*)d_ws + XB_OFF);

  const size_t need_xpre = (size_t)XB_OFF + (size_t)Bb * Ss * Ff * 2;
  const int xpre = (ws_size >= need_xpre) ? 1 : 0;

  init_kernel<<<1024, 256, 0, stream>>>(x, hbuf, flags, xb, xpre);

  void* args[] = {(void*)&x,  (void*)&xb, (void*)&Wf, (void*)&Uf,
                  (void*)&bf, (void*)&Wb, (void*)&Ub, (void*)&bb,
                  (void*)&out, (void*)&hbuf, (void*)&flags};
  hipError_t err;
  if (xpre) {
    err = hipLaunchCooperativeKernel((void*)bilstm_kernel<1>, dim3(2 * NWGD),
                                     dim3(256), args, 0, stream);
  } else {
    err = hipLaunchCooperativeKernel((void*)bilstm_kernel<0>, dim3(2 * NWGD),
                                     dim3(256), args, 0, stream);
  }
  if (err != hipSuccess) {
    // fallback: plain launch; grid (256 WGs, 2 waves/SIMD occupancy) is fully
    // co-resident on 256 CUs, and the barrier is monotone flags.
    if (xpre) {
      bilstm_kernel<1><<<dim3(2 * NWGD), dim3(256), 0, stream>>>(
          x, xb, Wf, Uf, bf, Wb, Ub, bb, out, hbuf, flags);
    } else {
      bilstm_kernel<0><<<dim3(2 * NWGD), dim3(256), 0, stream>>>(
          x, xb, Wf, Uf, bf, Wb, Ub, bb, out, hbuf, flags);
    }
  }
}

// Round 22
// 3027.270 us; speedup vs baseline: 1.2509x; 1.2509x over previous
//
#include <hip/hip_runtime.h>

#define Bb 64
#define Ss 512
#define Ff 512
#define Hh 512
#define GW 2048  // 4H
#define NWGD 128 // workgroups per direction (4 h-cols each)
#define FLAG_STRIDE 4   // u32 stride between flags = 16B

using bf16x8 = __attribute__((ext_vector_type(8))) short;
using f32x4  = __attribute__((ext_vector_type(4))) float;
typedef __attribute__((ext_vector_type(4))) short short4v;
typedef unsigned short u16;
typedef unsigned long long u64;

__device__ __forceinline__ short f2bf(float f) {
  unsigned u = __builtin_bit_cast(unsigned, f);
  u = (u + 0x7FFFu + ((u >> 16) & 1u)) >> 16;
  return (short)u;
}
__device__ __forceinline__ float fsigmoid(float x) {
  return 1.f / (1.f + __expf(-x));
}
__device__ __forceinline__ float ftanh(float x) {
  x = fminf(fmaxf(x, -15.f), 15.f);
  float e = __expf(-2.f * x);
  return (1.f - e) / (1.f + e);
}

// ws layout:
//   [0, 262144)          : h double buffer  [2][2dirs][64][512] bf16
//   [262144, +4096)      : arrival flags, [2 dirs][128 WGs], 16B apart
//   [278528, +33554432)  : optional x as bf16 [64][512][512]
#define HBUF_ELEMS (2 * Bb * Hh)
#define BAR_OFF    262144
#define XB_OFF     (262144 + 16384)
#define NFLAGW     (2 * NWGD * FLAG_STRIDE)

__global__ void init_kernel(const float* __restrict__ x, u16* hbuf0,
                            unsigned* flags, u16* xb, int do_conv) {
  const int gtid = blockIdx.x * blockDim.x + threadIdx.x;
  const int gstride = gridDim.x * blockDim.x;
  for (int i = gtid; i < NFLAGW; i += gstride) flags[i] = 0u;
  for (int i = gtid; i < HBUF_ELEMS; i += gstride) hbuf0[i] = 0;
  if (do_conv) {
    const float4* xv = (const float4*)x;
    const int n4 = Bb * Ss * Ff / 4;
    for (int i = gtid; i < n4; i += gstride) {
      float4 v = xv[i];
      short4v o;
      o[0] = f2bf(v.x); o[1] = f2bf(v.y); o[2] = f2bf(v.z); o[3] = f2bf(v.w);
      ((short4v*)xb)[i] = o;
    }
  }
}

template <int XPRE>
__global__ void __launch_bounds__(256, 2)
bilstm_kernel(const float* __restrict__ x, const u16* __restrict__ xb,
              const float* __restrict__ Wf, const float* __restrict__ Uf,
              const float* __restrict__ bfp, const float* __restrict__ Wb,
              const float* __restrict__ Ub, const float* __restrict__ bbp,
              float* __restrict__ out, u16* __restrict__ hbuf,
              unsigned* __restrict__ barflags) {
  const int tid = threadIdx.x, wg = blockIdx.x;
  const int dir = wg & 1;        // interleaved so each dir spans XCDs evenly
  const int blk = wg >> 1;       // 0..127, owns h-cols [blk*4, blk*4+4)
  const int wid = tid >> 6, lane = tid & 63;
  const int n = lane & 15, kgrp = lane >> 4;

  const float* W    = dir ? Wb : Wf;
  const float* Uu   = dir ? Ub : Uf;
  const float* bias = dir ? bbp : bfp;

  // one 16-col B-tile: col n -> gate g = n>>2, h-col = blk*4 + (n&3)
  const int gc = (n >> 2) * Hh + blk * 4 + (n & 3);
  const float b_own = bias[gc];

  // ---- weight fragments in registers (once): 16 k-slices each ----
  bf16x8 wfW[16], wfU[16];
#pragma unroll
  for (int ks = 0; ks < 16; ++ks) {
    bf16x8 w0, u0;
#pragma unroll
    for (int j = 0; j < 8; ++j) {
      const int k = ks * 32 + kgrp * 8 + j;
      w0[j] = f2bf(W[(size_t)k * GW + gc]);
      u0[j] = f2bf(Uu[(size_t)k * GW + gc]);
    }
    wfW[ks] = w0;
    wfU[ks] = u0;
  }

  const int arow = wid * 16 + n;  // batch row for A-fragments
  float c_reg[4] = {0.f, 0.f, 0.f, 0.f};

  u16* hb0 = hbuf;
  u16* hb1 = hbuf + HBUF_ELEMS;
  unsigned* flags  = barflags + (size_t)dir * NWGD * FLAG_STRIDE;
  unsigned* myflag = flags + (size_t)blk * FLAG_STRIDE;
  // per-lane poll slot: chunk c covers producers [32c, 32c+32)
  const unsigned* fpl = flags + (size_t)(lane & 31) * FLAG_STRIDE;

  float* out_hidden = out;
  float* out_h = out + (size_t)Bb * Ss * 2 * Hh;
  float* out_c = out_h + (size_t)Bb * 2 * Hh;

  bf16x8 afx[16];
  f32x4 accX;

  auto issue_x = [&](int t) {
    if (XPRE) {
      const u16* xbase = xb + ((size_t)arow * Ss + t) * Ff + kgrp * 8;
#pragma unroll
      for (int ks = 0; ks < 16; ++ks)
        afx[ks] = *(const bf16x8*)(xbase + ks * 32);
    }
  };
  auto finish_x = [&](int t) {
    f32x4 t0 = {0.f, 0.f, 0.f, 0.f};
    const float* xrow = x + ((size_t)arow * Ss + t) * Ff + kgrp * 8;
#pragma unroll
    for (int ks = 0; ks < 16; ++ks) {
      bf16x8 a;
      if (XPRE) {
        a = afx[ks];
      } else {
        const f32x4 p0 = *(const f32x4*)(xrow + ks * 32);
        const f32x4 p1 = *(const f32x4*)(xrow + ks * 32 + 4);
#pragma unroll
        for (int j = 0; j < 4; ++j) {
          a[j] = f2bf(p0[j]);
          a[j + 4] = f2bf(p1[j]);
        }
      }
      t0 = __builtin_amdgcn_mfma_f32_16x16x32_bf16(a, wfW[ks], t0, 0, 0, 0);
    }
    accX = t0;
  };

  // prologue: x-part for step 0
  {
    const int t0i = dir ? (Ss - 1) : 0;
    issue_x(t0i);
    finish_x(t0i);
  }

  for (int s = 0; s < Ss; ++s) {
    u16* hcur = (s & 1) ? hb1 : hb0;
    u16* hnxt = (s & 1) ? hb0 : hb1;
    const bool last = (s == Ss - 1);

    // ---- chunked per-wave poll + h loads (R19-proven): chunk c gates on
    //      producers [32c,32c+32), then issues those 4 sc-bypass loads.
    //      Straggler wait overlaps earlier chunks' load RT. ----
    const u16* hbase = hcur + (size_t)dir * Bb * Hh + (size_t)arow * Hh + kgrp * 8;
    bf16x8 ah[16];
    const unsigned tgt = (unsigned)s;
#pragma unroll
    for (int c = 0; c < 4; ++c) {
      if (s > 0) {
        const unsigned* fp = fpl + (size_t)(c * 32) * FLAG_STRIDE;
        for (;;) {
          const unsigned a = __hip_atomic_load(fp, __ATOMIC_RELAXED,
                                               __HIP_MEMORY_SCOPE_AGENT);
          if (__all(a >= tgt)) break;
          __builtin_amdgcn_s_sleep(1);
        }
        __builtin_amdgcn_sched_barrier(0);
      }
#pragma unroll
      for (int k2 = 0; k2 < 4; ++k2) {
        const int ks = c * 4 + k2;
        asm volatile("global_load_dwordx4 %0, %1, off offset:%c2 sc0 sc1"
                     : "=v"(ah[ks])
                     : "v"(hbase), "i"(ks * 64)
                     : "memory");
      }
    }

    // ---- split-wait h@U (single change vs R19): chunks 0-2 retired during
    //      the chunk polls (each poll-load retire drains older h-loads), so
    //      vmcnt(4) passes immediately and 12 MFMAs overlap chunk-3's RT ----
    f32x4 accA = accX;
    f32x4 accB = {0.f, 0.f, 0.f, 0.f};
    asm volatile("s_waitcnt vmcnt(4)" ::: "memory");
    __builtin_amdgcn_sched_barrier(0);
#pragma unroll
    for (int ks = 0; ks < 6; ++ks) {
      accA = __builtin_amdgcn_mfma_f32_16x16x32_bf16(ah[2 * ks], wfU[2 * ks], accA, 0, 0, 0);
      accB = __builtin_amdgcn_mfma_f32_16x16x32_bf16(ah[2 * ks + 1], wfU[2 * ks + 1], accB, 0, 0, 0);
    }
    asm volatile("s_waitcnt vmcnt(0)" ::: "memory");
    __builtin_amdgcn_sched_barrier(0);
#pragma unroll
    for (int ks = 6; ks < 8; ++ks) {
      accA = __builtin_amdgcn_mfma_f32_16x16x32_bf16(ah[2 * ks], wfU[2 * ks], accA, 0, 0, 0);
      accB = __builtin_amdgcn_mfma_f32_16x16x32_bf16(ah[2 * ks + 1], wfU[2 * ks + 1], accB, 0, 0, 0);
    }
    f32x4 acc;
#pragma unroll
    for (int r = 0; r < 4; ++r) acc[r] = accA[r] + accB[r];

    const int tnext = dir ? (Ss - 2 - s) : (s + 1);
    if (!last) issue_x(tnext);  // loads in flight under combine

    // ---- wave-local gate combine (valid in lanes n<4) ----
    float hv[4];
#pragma unroll
    for (int r = 0; r < 4; ++r) {
      const float a = acc[r] + b_own;
      const float act = ((n >> 2) == 2) ? ftanh(a) : fsigmoid(a);
      const float f4  = __shfl_xor(act, 4);   // lane n<4: forget gate
      const float g8  = __shfl_xor(act, 8);   // lane n<4: cell gate
      const float o12 = __shfl_xor(act, 12);  // lane n<4: output gate
      c_reg[r] = f4 * c_reg[r] + act * g8;
      hv[r] = o12 * ftanh(c_reg[r]);
    }
    float hnb[4];
#pragma unroll
    for (int r = 0; r < 4; ++r) hnb[r] = __shfl_xor(hv[r], 1);
    float cnb[4];
    if (last) {
#pragma unroll
      for (int r = 0; r < 4; ++r) cnb[r] = __shfl_xor(c_reg[r], 1);
    }

    const bool owner = ((n & 1) == 0 && n < 4);  // lanes n in {0,2}
    const int col = blk * 4 + n;

    // ---- h store ONLY before the drain ----
    if (owner) {
#pragma unroll
      for (int r = 0; r < 4; ++r) {
        const int row = wid * 16 + kgrp * 4 + r;
        const unsigned hp = (unsigned)(unsigned short)f2bf(hv[r]) |
                            ((unsigned)(unsigned short)f2bf(hnb[r]) << 16);
        // write-through (agent scope); drained at syncthreads before the flag
        __hip_atomic_store(
            (unsigned*)(hnxt + (size_t)dir * Bb * Hh + (size_t)row * Hh + col),
            hp, __ATOMIC_RELAXED, __HIP_MEMORY_SCOPE_AGENT);
      }
    }

    // ---- arrive (R19-proven: syncthreads rendezvous + tid0 flag) ----
    if (!last) {
      __syncthreads();  // all waves' h stores drained (vmcnt 0) before arrive
      if (tid == 0)
        __hip_atomic_store(myflag, (unsigned)(s + 1), __ATOMIC_RELAXED,
                           __HIP_MEMORY_SCOPE_AGENT);
    }

    // ---- out stores after the flag (R19-proven placement) ----
    if (owner) {
#pragma unroll
      for (int r = 0; r < 4; ++r) {
        const int row = wid * 16 + kgrp * 4 + r;
        float2 o2;
        o2.x = hv[r]; o2.y = hnb[r];
        __hip_atomic_store(
            (u64*)(out_hidden + (size_t)row * Ss * 2 * Hh + (size_t)s * 2 * Hh +
                   (size_t)dir * Hh + col),
            __builtin_bit_cast(u64, o2), __ATOMIC_RELAXED,
            __HIP_MEMORY_SCOPE_AGENT);
        if (last) {  // end-of-kernel writeback handles visibility for these
          *(float2*)(out_h + (size_t)row * 2 * Hh + (size_t)dir * Hh + col) = o2;
          if (dir == 0) {  // bug-faithful: c_t = [c_fwd, c_fwd]
            float2 c2;
            c2.x = c_reg[r]; c2.y = cnb[r];
            *(float2*)(out_c + (size_t)row * 2 * Hh + col) = c2;
            *(float2*)(out_c + (size_t)row * 2 * Hh + Hh + col) = c2;
          }
        }
      }
    }

    // ---- x@W for the next step (register MFMAs, overlaps flag propagation) ----
    if (!last) finish_x(tnext);
  }
}

extern "C" void kernel_launch(void* const* d_in, const int* in_sizes, int n_in,
                              void* d_out, int out_size, void* d_ws, size_t ws_size,
                              hipStream_t stream) {
  const float* x  = (const float*)d_in[0];
  const float* Wf = (const float*)d_in[1];
  const float* Uf = (const float*)d_in[2];
  const float* bf = (const float*)d_in[3];
  const float* Wb = (const float*)d_in[4];
  const float* Ub = (const float*)d_in[5];
  const float* bb = (const float*)d_in[6];
  float* out = (float*)d_out;

  u16* hbuf       = (u16*)d_ws;
  unsigned* flags = (unsigned*)((char*)d_ws + BAR_OFF);
  u16* xb         = (u16*)((char*)d_ws + XB_OFF);

  const size_t need_xpre = (size_t)XB_OFF + (size_t)Bb * Ss * Ff * 2;
  const int xpre = (ws_size >= need_xpre) ? 1 : 0;

  init_kernel<<<1024, 256, 0, stream>>>(x, hbuf, flags, xb, xpre);

  void* args[] = {(void*)&x,  (void*)&xb, (void*)&Wf, (void*)&Uf,
                  (void*)&bf, (void*)&Wb, (void*)&Ub, (void*)&bb,
                  (void*)&out, (void*)&hbuf, (void*)&flags};
  hipError_t err;
  if (xpre) {
    err = hipLaunchCooperativeKernel((void*)bilstm_kernel<1>, dim3(2 * NWGD),
                                     dim3(256), args, 0, stream);
  } else {
    err = hipLaunchCooperativeKernel((void*)bilstm_kernel<0>, dim3(2 * NWGD),
                                     dim3(256), args, 0, stream);
  }
  if (err != hipSuccess) {
    // fallback: plain launch; grid (256 WGs, 2 waves/SIMD occupancy) is fully
    // co-resident on 256 CUs, and the barrier is monotone flags.
    if (xpre) {
      bilstm_kernel<1><<<dim3(2 * NWGD), dim3(256), 0, stream>>>(
          x, xb, Wf, Uf, bf, Wb, Ub, bb, out, hbuf, flags);
    } else {
      bilstm_kernel<0><<<dim3(2 * NWGD), dim3(256), 0, stream>>>(
          x, xb, Wf, Uf, bf, Wb, Ub, bb, out, hbuf, flags);
    }
  }
}

// Round 23
// 2337.381 us; speedup vs baseline: 1.6201x; 1.2952x over previous
//
#include <hip/hip_runtime.h>

#define Bb 64
#define Ss 512
#define Ff 512
#define Hh 512
#define GW 2048  // 4H
#define NWGD 64  // workgroups per direction (8 h-cols each)
#define FLAG_STRIDE 4   // u32 stride between flags = 16B

using bf16x8 = __attribute__((ext_vector_type(8))) short;
using f32x4  = __attribute__((ext_vector_type(4))) float;
typedef __attribute__((ext_vector_type(4))) short short4v;
typedef unsigned short u16;
typedef unsigned long long u64;

__device__ __forceinline__ short f2bf(float f) {
  unsigned u = __builtin_bit_cast(unsigned, f);
  u = (u + 0x7FFFu + ((u >> 16) & 1u)) >> 16;
  return (short)u;
}
__device__ __forceinline__ float fsigmoid(float x) {
  return 1.f / (1.f + __expf(-x));
}
__device__ __forceinline__ float ftanh(float x) {
  x = fminf(fmaxf(x, -15.f), 15.f);
  float e = __expf(-2.f * x);
  return (1.f - e) / (1.f + e);
}

// ws layout:
//   [0, 262144)          : h double buffer  [2][2dirs][64][512] bf16
//   [262144, +2048)      : arrival flags, [2 dirs][64 WGs], 16B apart
//   [278528, +33554432)  : optional x as bf16 [64][512][512]
#define HBUF_ELEMS (2 * Bb * Hh)
#define BAR_OFF    262144
#define XB_OFF     (262144 + 16384)
#define NFLAGW     (2 * NWGD * FLAG_STRIDE)

__global__ void init_kernel(const float* __restrict__ x, u16* hbuf0,
                            unsigned* flags, u16* xb, int do_conv) {
  const int gtid = blockIdx.x * blockDim.x + threadIdx.x;
  const int gstride = gridDim.x * blockDim.x;
  for (int i = gtid; i < NFLAGW; i += gstride) flags[i] = 0u;
  for (int i = gtid; i < HBUF_ELEMS; i += gstride) hbuf0[i] = 0;
  if (do_conv) {
    const float4* xv = (const float4*)x;
    const int n4 = Bb * Ss * Ff / 4;
    for (int i = gtid; i < n4; i += gstride) {
      float4 v = xv[i];
      short4v o;
      o[0] = f2bf(v.x); o[1] = f2bf(v.y); o[2] = f2bf(v.z); o[3] = f2bf(v.w);
      ((short4v*)xb)[i] = o;
    }
  }
}

template <int XPRE>
__global__ void __launch_bounds__(256, 1)
bilstm_kernel(const float* __restrict__ x, const u16* __restrict__ xb,
              const float* __restrict__ Wf, const float* __restrict__ Uf,
              const float* __restrict__ bfp, const float* __restrict__ Wb,
              const float* __restrict__ Ub, const float* __restrict__ bbp,
              float* __restrict__ out, u16* __restrict__ hbuf,
              unsigned* __restrict__ barflags) {
  const int tid = threadIdx.x, wg = blockIdx.x;
  const int dir = wg & 1;        // interleaved so each dir spans XCDs evenly
  const int blk = wg >> 1;       // 0..63, owns h-cols [blk*8, blk*8+8)
  const int wid = tid >> 6, lane = tid & 63;
  const int n = lane & 15, kgrp = lane >> 4;

  const float* W    = dir ? Wb : Wf;
  const float* Uu   = dir ? Ub : Uf;
  const float* bias = dir ? bbp : bfp;

  // two 16-col B-tiles: tile t, col n -> gate g = t*2 + (n>>3), col c = n&7
  // t=0: {i,f}; t=1: {g,o}
  bf16x8 wfW[2][16], wfU[2][16];
  float b_own[2];
#pragma unroll
  for (int t = 0; t < 2; ++t) {
    const int gc = (t * 2 + (n >> 3)) * Hh + blk * 8 + (n & 7);
    b_own[t] = bias[gc];
#pragma unroll
    for (int ks = 0; ks < 16; ++ks) {
      bf16x8 w0, u0;
#pragma unroll
      for (int j = 0; j < 8; ++j) {
        const int k = ks * 32 + kgrp * 8 + j;
        w0[j] = f2bf(W[(size_t)k * GW + gc]);
        u0[j] = f2bf(Uu[(size_t)k * GW + gc]);
      }
      wfW[t][ks] = w0;
      wfU[t][ks] = u0;
    }
  }

  const int arow = wid * 16 + n;  // batch row for A-fragments
  float c_reg[4] = {0.f, 0.f, 0.f, 0.f};

  u16* hb0 = hbuf;
  u16* hb1 = hbuf + HBUF_ELEMS;
  unsigned* flags  = barflags + (size_t)dir * NWGD * FLAG_STRIDE;
  unsigned* myflag = flags + (size_t)blk * FLAG_STRIDE;
  // per-lane poll slot: chunk c covers producers [32c, 32c+32)
  const unsigned* fpl = flags + (size_t)(lane & 31) * FLAG_STRIDE;

  float* out_hidden = out;
  float* out_h = out + (size_t)Bb * Ss * 2 * Hh;
  float* out_c = out_h + (size_t)Bb * 2 * Hh;

  bf16x8 afx[16];
  f32x4 accX0, accX1;

  auto issue_x = [&](int t) {
    if (XPRE) {
      const u16* xbase = xb + ((size_t)arow * Ss + t) * Ff + kgrp * 8;
#pragma unroll
      for (int ks = 0; ks < 16; ++ks)
        afx[ks] = *(const bf16x8*)(xbase + ks * 32);
    }
  };
  auto finish_x = [&](int t) {
    f32x4 t0 = {0.f, 0.f, 0.f, 0.f};
    f32x4 t1 = {0.f, 0.f, 0.f, 0.f};
    const float* xrow = x + ((size_t)arow * Ss + t) * Ff + kgrp * 8;
#pragma unroll
    for (int ks = 0; ks < 16; ++ks) {
      bf16x8 a;
      if (XPRE) {
        a = afx[ks];
      } else {
        const f32x4 p0 = *(const f32x4*)(xrow + ks * 32);
        const f32x4 p1 = *(const f32x4*)(xrow + ks * 32 + 4);
#pragma unroll
        for (int j = 0; j < 4; ++j) {
          a[j] = f2bf(p0[j]);
          a[j + 4] = f2bf(p1[j]);
        }
      }
      t0 = __builtin_amdgcn_mfma_f32_16x16x32_bf16(a, wfW[0][ks], t0, 0, 0, 0);
      t1 = __builtin_amdgcn_mfma_f32_16x16x32_bf16(a, wfW[1][ks], t1, 0, 0, 0);
    }
    accX0 = t0;
    accX1 = t1;
  };

  // prologue: x-part for step 0
  {
    const int t0i = dir ? (Ss - 1) : 0;
    issue_x(t0i);
    finish_x(t0i);
  }

  for (int s = 0; s < Ss; ++s) {
    u16* hcur = (s & 1) ? hb1 : hb0;
    u16* hnxt = (s & 1) ? hb0 : hb1;
    const bool last = (s == Ss - 1);

    // ---- 2-chunk poll + h loads: chunk c gates on producers [32c,32c+32)
    //      (their h cols [256c,256c+256) = k-slices [8c,8c+8)), then issues
    //      those 8 sc-bypass loads. Straggler wait overlaps chunk-0 load RT.
    const u16* hbase = hcur + (size_t)dir * Bb * Hh + (size_t)arow * Hh + kgrp * 8;
    bf16x8 ah[16];
    const unsigned tgt = (unsigned)s;
#pragma unroll
    for (int c = 0; c < 2; ++c) {
      if (s > 0) {
        const unsigned* fp = fpl + (size_t)(c * 32) * FLAG_STRIDE;
        for (;;) {
          const unsigned a = __hip_atomic_load(fp, __ATOMIC_RELAXED,
                                               __HIP_MEMORY_SCOPE_AGENT);
          if (__all(a >= tgt)) break;
          __builtin_amdgcn_s_sleep(1);
        }
        __builtin_amdgcn_sched_barrier(0);
      }
#pragma unroll
      for (int k2 = 0; k2 < 8; ++k2) {
        const int ks = c * 8 + k2;
        asm volatile("global_load_dwordx4 %0, %1, off offset:%c2 sc0 sc1"
                     : "=v"(ah[ks])
                     : "v"(hbase), "i"(ks * 64)
                     : "memory");
      }
    }
    asm volatile("s_waitcnt vmcnt(0)" ::: "memory");
    __builtin_amdgcn_sched_barrier(0);

    // ---- h@U: two independent chains (one per tile) on x@W accumulators ----
    f32x4 acc0 = accX0, acc1 = accX1;
#pragma unroll
    for (int ks = 0; ks < 16; ++ks) {
      acc0 = __builtin_amdgcn_mfma_f32_16x16x32_bf16(ah[ks], wfU[0][ks], acc0, 0, 0, 0);
      acc1 = __builtin_amdgcn_mfma_f32_16x16x32_bf16(ah[ks], wfU[1][ks], acc1, 0, 0, 0);
    }

    const int tnext = dir ? (Ss - 2 - s) : (s + 1);
    if (!last) issue_x(tnext);  // loads in flight under combine

    // ---- gate combine: acc0 = i|f, acc1 = g|o (split at n=8) ----
    float hv[4];
#pragma unroll
    for (int r = 0; r < 4; ++r) {
      const float a0 = acc0[r] + b_own[0];
      const float a1 = acc1[r] + b_own[1];
      const float act0 = fsigmoid(a0);                        // n<8: i, n>=8: f
      const float act1 = (n < 8) ? ftanh(a1) : fsigmoid(a1);  // n<8: g, n>=8: o
      const float fv = __shfl_xor(act0, 8);                   // n<8: f
      const float ov = __shfl_xor(act1, 8);                   // n<8: o
      c_reg[r] = fv * c_reg[r] + act0 * act1;                 // f*c + i*g
      hv[r] = ov * ftanh(c_reg[r]);
    }
    float hnb[4];
#pragma unroll
    for (int r = 0; r < 4; ++r) hnb[r] = __shfl_xor(hv[r], 1);
    float cnb[4];
    if (last) {
#pragma unroll
      for (int r = 0; r < 4; ++r) cnb[r] = __shfl_xor(c_reg[r], 1);
    }

    const bool owner = (n < 8) && ((n & 1) == 0);  // lanes n in {0,2,4,6}
    const int col = blk * 8 + n;

    // ---- h store ONLY before the drain ----
    if (owner) {
#pragma unroll
      for (int r = 0; r < 4; ++r) {
        const int row = wid * 16 + kgrp * 4 + r;
        const unsigned hp = (unsigned)(unsigned short)f2bf(hv[r]) |
                            ((unsigned)(unsigned short)f2bf(hnb[r]) << 16);
        // write-through (agent scope); drained at syncthreads before the flag
        __hip_atomic_store(
            (unsigned*)(hnxt + (size_t)dir * Bb * Hh + (size_t)row * Hh + col),
            hp, __ATOMIC_RELAXED, __HIP_MEMORY_SCOPE_AGENT);
      }
    }

    // ---- arrive (R19-proven: syncthreads rendezvous + tid0 flag) ----
    if (!last) {
      __syncthreads();  // all waves' h stores drained (vmcnt 0) before arrive
      if (tid == 0)
        __hip_atomic_store(myflag, (unsigned)(s + 1), __ATOMIC_RELAXED,
                           __HIP_MEMORY_SCOPE_AGENT);
    }

    // ---- out stores after the flag (R19-proven placement) ----
    if (owner) {
#pragma unroll
      for (int r = 0; r < 4; ++r) {
        const int row = wid * 16 + kgrp * 4 + r;
        float2 o2;
        o2.x = hv[r]; o2.y = hnb[r];
        __hip_atomic_store(
            (u64*)(out_hidden + (size_t)row * Ss * 2 * Hh + (size_t)s * 2 * Hh +
                   (size_t)dir * Hh + col),
            __builtin_bit_cast(u64, o2), __ATOMIC_RELAXED,
            __HIP_MEMORY_SCOPE_AGENT);
        if (last) {  // end-of-kernel writeback handles visibility for these
          *(float2*)(out_h + (size_t)row * 2 * Hh + (size_t)dir * Hh + col) = o2;
          if (dir == 0) {  // bug-faithful: c_t = [c_fwd, c_fwd]
            float2 c2;
            c2.x = c_reg[r]; c2.y = cnb[r];
            *(float2*)(out_c + (size_t)row * 2 * Hh + col) = c2;
            *(float2*)(out_c + (size_t)row * 2 * Hh + Hh + col) = c2;
          }
        }
      }
    }

    // ---- x@W for the next step (register MFMAs, overlaps flag propagation) ----
    if (!last) finish_x(tnext);
  }
}

extern "C" void kernel_launch(void* const* d_in, const int* in_sizes, int n_in,
                              void* d_out, int out_size, void* d_ws, size_t ws_size,
                              hipStream_t stream) {
  const float* x  = (const float*)d_in[0];
  const float* Wf = (const float*)d_in[1];
  const float* Uf = (const float*)d_in[2];
  const float* bf = (const float*)d_in[3];
  const float* Wb = (const float*)d_in[4];
  const float* Ub = (const float*)d_in[5];
  const float* bb = (const float*)d_in[6];
  float* out = (float*)d_out;

  u16* hbuf       = (u16*)d_ws;
  unsigned* flags = (unsigned*)((char*)d_ws + BAR_OFF);
  u16* xb         = (u16*)((char*)d_ws + XB_OFF);

  const size_t need_xpre = (size_t)XB_OFF + (size_t)Bb * Ss * Ff * 2;
  const int xpre = (ws_size >= need_xpre) ? 1 : 0;

  init_kernel<<<1024, 256, 0, stream>>>(x, hbuf, flags, xb, xpre);

  void* args[] = {(void*)&x,  (void*)&xb, (void*)&Wf, (void*)&Uf,
                  (void*)&bf, (void*)&Wb, (void*)&Ub, (void*)&bb,
                  (void*)&out, (void*)&hbuf, (void*)&flags};
  hipError_t err;
  if (xpre) {
    err = hipLaunchCooperativeKernel((void*)bilstm_kernel<1>, dim3(2 * NWGD),
                                     dim3(256), args, 0, stream);
  } else {
    err = hipLaunchCooperativeKernel((void*)bilstm_kernel<0>, dim3(2 * NWGD),
                                     dim3(256), args, 0, stream);
  }
  if (err != hipSuccess) {
    // fallback: plain launch; 128 WGs at 1 WG/CU are fully co-resident on
    // 256 CUs, and the barrier is monotone flags.
    if (xpre) {
      bilstm_kernel<1><<<dim3(2 * NWGD), dim3(256), 0, stream>>>(
          x, xb, Wf, Uf, bf, Wb, Ub, bb, out, hbuf, flags);
    } else {
      bilstm_kernel<0><<<dim3(2 * NWGD), dim3(256), 0, stream>>>(
          x, xb, Wf, Uf, bf, Wb, Ub, bb, out, hbuf, flags);
    }
  }
}

// Round 24
// 2322.356 us; speedup vs baseline: 1.6305x; 1.0065x over previous
//
#include <hip/hip_runtime.h>

#define Bb 64
#define Ss 512
#define Ff 512
#define Hh 512
#define GW 2048  // 4H
#define NWGD 64  // workgroups per direction (8 h-cols each)
#define FLAG_STRIDE 4   // u32 stride between flags = 16B

using bf16x8 = __attribute__((ext_vector_type(8))) short;
using f32x4  = __attribute__((ext_vector_type(4))) float;
typedef __attribute__((ext_vector_type(4))) short short4v;
typedef unsigned short u16;
typedef unsigned long long u64;

__device__ __forceinline__ short f2bf(float f) {
  unsigned u = __builtin_bit_cast(unsigned, f);
  u = (u + 0x7FFFu + ((u >> 16) & 1u)) >> 16;
  return (short)u;
}
__device__ __forceinline__ float fsigmoid(float x) {
  return 1.f / (1.f + __expf(-x));
}
__device__ __forceinline__ float ftanh(float x) {
  x = fminf(fmaxf(x, -15.f), 15.f);
  float e = __expf(-2.f * x);
  return (1.f - e) / (1.f + e);
}

// ws layout:
//   [0, 262144)          : h double buffer  [2][2dirs][64][512] bf16
//   [262144, +2048)      : arrival flags, [2 dirs][64 WGs], 16B apart
//   [278528, +33554432)  : optional x as bf16 [64][512][512]
#define HBUF_ELEMS (2 * Bb * Hh)
#define BAR_OFF    262144
#define XB_OFF     (262144 + 16384)
#define NFLAGW     (2 * NWGD * FLAG_STRIDE)

__global__ void init_kernel(const float* __restrict__ x, u16* hbuf0,
                            unsigned* flags, u16* xb, int do_conv) {
  const int gtid = blockIdx.x * blockDim.x + threadIdx.x;
  const int gstride = gridDim.x * blockDim.x;
  for (int i = gtid; i < NFLAGW; i += gstride) flags[i] = 0u;
  for (int i = gtid; i < HBUF_ELEMS; i += gstride) hbuf0[i] = 0;
  if (do_conv) {
    const float4* xv = (const float4*)x;
    const int n4 = Bb * Ss * Ff / 4;
    for (int i = gtid; i < n4; i += gstride) {
      float4 v = xv[i];
      short4v o;
      o[0] = f2bf(v.x); o[1] = f2bf(v.y); o[2] = f2bf(v.z); o[3] = f2bf(v.w);
      ((short4v*)xb)[i] = o;
    }
  }
}

template <int XPRE>
__global__ void __launch_bounds__(256, 1)
bilstm_kernel(const float* __restrict__ x, const u16* __restrict__ xb,
              const float* __restrict__ Wf, const float* __restrict__ Uf,
              const float* __restrict__ bfp, const float* __restrict__ Wb,
              const float* __restrict__ Ub, const float* __restrict__ bbp,
              float* __restrict__ out, u16* __restrict__ hbuf,
              unsigned* __restrict__ barflags) {
  const int tid = threadIdx.x, wg = blockIdx.x;
  const int dir = wg & 1;        // interleaved so each dir spans XCDs evenly
  const int blk = wg >> 1;       // 0..63, owns h-cols [blk*8, blk*8+8)
  const int wid = tid >> 6, lane = tid & 63;
  const int n = lane & 15, kgrp = lane >> 4;

  const float* W    = dir ? Wb : Wf;
  const float* Uu   = dir ? Ub : Uf;
  const float* bias = dir ? bbp : bfp;

  // two 16-col B-tiles: tile t, col n -> gate g = t*2 + (n>>3), col c = n&7
  // t=0: {i,f}; t=1: {g,o}
  bf16x8 wfW[2][16], wfU[2][16];
  float b_own[2];
#pragma unroll
  for (int t = 0; t < 2; ++t) {
    const int gc = (t * 2 + (n >> 3)) * Hh + blk * 8 + (n & 7);
    b_own[t] = bias[gc];
#pragma unroll
    for (int ks = 0; ks < 16; ++ks) {
      bf16x8 w0, u0;
#pragma unroll
      for (int j = 0; j < 8; ++j) {
        const int k = ks * 32 + kgrp * 8 + j;
        w0[j] = f2bf(W[(size_t)k * GW + gc]);
        u0[j] = f2bf(Uu[(size_t)k * GW + gc]);
      }
      wfW[t][ks] = w0;
      wfU[t][ks] = u0;
    }
  }

  const int arow = wid * 16 + n;  // batch row for A-fragments
  float c_reg[4] = {0.f, 0.f, 0.f, 0.f};

  u16* hb0 = hbuf;
  u16* hb1 = hbuf + HBUF_ELEMS;
  unsigned* flags  = barflags + (size_t)dir * NWGD * FLAG_STRIDE;
  unsigned* myflag = flags + (size_t)blk * FLAG_STRIDE;
  // per-lane poll slot: chunk c covers producers [32c, 32c+32)
  const unsigned* fpl = flags + (size_t)(lane & 31) * FLAG_STRIDE;

  float* out_hidden = out;
  float* out_h = out + (size_t)Bb * Ss * 2 * Hh;
  float* out_c = out_h + (size_t)Bb * 2 * Hh;

  bf16x8 afx[16];
  f32x4 accX0, accX1;

  auto issue_x = [&](int t) {
    if (XPRE) {
      const u16* xbase = xb + ((size_t)arow * Ss + t) * Ff + kgrp * 8;
#pragma unroll
      for (int ks = 0; ks < 16; ++ks)
        afx[ks] = *(const bf16x8*)(xbase + ks * 32);
    }
  };
  auto finish_x = [&](int t) {
    f32x4 t0 = {0.f, 0.f, 0.f, 0.f};
    f32x4 t1 = {0.f, 0.f, 0.f, 0.f};
    const float* xrow = x + ((size_t)arow * Ss + t) * Ff + kgrp * 8;
#pragma unroll
    for (int ks = 0; ks < 16; ++ks) {
      bf16x8 a;
      if (XPRE) {
        a = afx[ks];
      } else {
        const f32x4 p0 = *(const f32x4*)(xrow + ks * 32);
        const f32x4 p1 = *(const f32x4*)(xrow + ks * 32 + 4);
#pragma unroll
        for (int j = 0; j < 4; ++j) {
          a[j] = f2bf(p0[j]);
          a[j + 4] = f2bf(p1[j]);
        }
      }
      t0 = __builtin_amdgcn_mfma_f32_16x16x32_bf16(a, wfW[0][ks], t0, 0, 0, 0);
      t1 = __builtin_amdgcn_mfma_f32_16x16x32_bf16(a, wfW[1][ks], t1, 0, 0, 0);
    }
    accX0 = t0;
    accX1 = t1;
  };

  // prologue: x-part for step 0
  {
    const int t0i = dir ? (Ss - 1) : 0;
    issue_x(t0i);
    finish_x(t0i);
  }

  for (int s = 0; s < Ss; ++s) {
    u16* hcur = (s & 1) ? hb1 : hb0;
    u16* hnxt = (s & 1) ? hb0 : hb1;
    const bool last = (s == Ss - 1);

    // ---- 2-chunk poll + h loads: chunk c gates on producers [32c,32c+32)
    //      (their h cols [256c,256c+256) = k-slices [8c,8c+8)), then issues
    //      those 8 sc-bypass loads. Straggler wait overlaps chunk-0 load RT.
    const u16* hbase = hcur + (size_t)dir * Bb * Hh + (size_t)arow * Hh + kgrp * 8;
    bf16x8 ah[16];
    const unsigned tgt = (unsigned)s;
#pragma unroll
    for (int c = 0; c < 2; ++c) {
      if (s > 0) {
        const unsigned* fp = fpl + (size_t)(c * 32) * FLAG_STRIDE;
        for (;;) {
          const unsigned a = __hip_atomic_load(fp, __ATOMIC_RELAXED,
                                               __HIP_MEMORY_SCOPE_AGENT);
          if (__all(a >= tgt)) break;
          __builtin_amdgcn_s_sleep(1);
        }
        __builtin_amdgcn_sched_barrier(0);
      }
#pragma unroll
      for (int k2 = 0; k2 < 8; ++k2) {
        const int ks = c * 8 + k2;
        asm volatile("global_load_dwordx4 %0, %1, off offset:%c2 sc0 sc1"
                     : "=v"(ah[ks])
                     : "v"(hbase), "i"(ks * 64)
                     : "memory");
      }
    }
    asm volatile("s_waitcnt vmcnt(0)" ::: "memory");
    __builtin_amdgcn_sched_barrier(0);

    // ---- h@U: two independent chains (one per tile) on x@W accumulators ----
    f32x4 acc0 = accX0, acc1 = accX1;
#pragma unroll
    for (int ks = 0; ks < 16; ++ks) {
      acc0 = __builtin_amdgcn_mfma_f32_16x16x32_bf16(ah[ks], wfU[0][ks], acc0, 0, 0, 0);
      acc1 = __builtin_amdgcn_mfma_f32_16x16x32_bf16(ah[ks], wfU[1][ks], acc1, 0, 0, 0);
    }

    const int tnext = dir ? (Ss - 2 - s) : (s + 1);
    if (!last) issue_x(tnext);  // loads in flight under combine

    // ---- gate combine: acc0 = i|f, acc1 = g|o (split at n=8) ----
    float hv[4];
#pragma unroll
    for (int r = 0; r < 4; ++r) {
      const float a0 = acc0[r] + b_own[0];
      const float a1 = acc1[r] + b_own[1];
      const float act0 = fsigmoid(a0);                        // n<8: i, n>=8: f
      const float act1 = (n < 8) ? ftanh(a1) : fsigmoid(a1);  // n<8: g, n>=8: o
      const float fv = __shfl_xor(act0, 8);                   // n<8: f
      const float ov = __shfl_xor(act1, 8);                   // n<8: o
      c_reg[r] = fv * c_reg[r] + act0 * act1;                 // f*c + i*g
      hv[r] = ov * ftanh(c_reg[r]);
    }
    float hnb[4];
#pragma unroll
    for (int r = 0; r < 4; ++r) hnb[r] = __shfl_xor(hv[r], 1);
    float cnb[4];
    if (last) {
#pragma unroll
      for (int r = 0; r < 4; ++r) cnb[r] = __shfl_xor(c_reg[r], 1);
    }

    const bool owner = (n < 8) && ((n & 1) == 0);  // lanes n in {0,2,4,6}
    const int col = blk * 8 + n;

    // ---- h store ONLY before the drain ----
    if (owner) {
#pragma unroll
      for (int r = 0; r < 4; ++r) {
        const int row = wid * 16 + kgrp * 4 + r;
        const unsigned hp = (unsigned)(unsigned short)f2bf(hv[r]) |
                            ((unsigned)(unsigned short)f2bf(hnb[r]) << 16);
        // write-through (agent scope); drained at syncthreads before the flag
        __hip_atomic_store(
            (unsigned*)(hnxt + (size_t)dir * Bb * Hh + (size_t)row * Hh + col),
            hp, __ATOMIC_RELAXED, __HIP_MEMORY_SCOPE_AGENT);
      }
    }

    // ---- arrive (R19-proven: syncthreads rendezvous + tid0 flag) ----
    if (!last) {
      __syncthreads();  // all waves' h stores drained (vmcnt 0) before arrive
      if (tid == 0)
        __hip_atomic_store(myflag, (unsigned)(s + 1), __ATOMIC_RELAXED,
                           __HIP_MEMORY_SCOPE_AGENT);
    }

    // ---- out stores after the flag: PLAIN cached stores (single change vs
    //      R23). out_hidden is producer-private: no reader in-kernel, host
    //      visibility via kernel-end flush. Acks retire at local L2 (fast),
    //      L2 merges the 32B partial lines before HBM writeback. ----
    if (owner) {
#pragma unroll
      for (int r = 0; r < 4; ++r) {
        const int row = wid * 16 + kgrp * 4 + r;
        float2 o2;
        o2.x = hv[r]; o2.y = hnb[r];
        *(float2*)(out_hidden + (size_t)row * Ss * 2 * Hh + (size_t)s * 2 * Hh +
                   (size_t)dir * Hh + col) = o2;
        if (last) {
          *(float2*)(out_h + (size_t)row * 2 * Hh + (size_t)dir * Hh + col) = o2;
          if (dir == 0) {  // bug-faithful: c_t = [c_fwd, c_fwd]
            float2 c2;
            c2.x = c_reg[r]; c2.y = cnb[r];
            *(float2*)(out_c + (size_t)row * 2 * Hh + col) = c2;
            *(float2*)(out_c + (size_t)row * 2 * Hh + Hh + col) = c2;
          }
        }
      }
    }

    // ---- x@W for the next step (register MFMAs, overlaps flag propagation) ----
    if (!last) finish_x(tnext);
  }
}

extern "C" void kernel_launch(void* const* d_in, const int* in_sizes, int n_in,
                              void* d_out, int out_size, void* d_ws, size_t ws_size,
                              hipStream_t stream) {
  const float* x  = (const float*)d_in[0];
  const float* Wf = (const float*)d_in[1];
  const float* Uf = (const float*)d_in[2];
  const float* bf = (const float*)d_in[3];
  const float* Wb = (const float*)d_in[4];
  const float* Ub = (const float*)d_in[5];
  const float* bb = (const float*)d_in[6];
  float* out = (float*)d_out;

  u16* hbuf       = (u16*)d_ws;
  unsigned* flags = (unsigned*)((char*)d_ws + BAR_OFF);
  u16* xb         = (u16*)((char*)d_ws + XB_OFF);

  const size_t need_xpre = (size_t)XB_OFF + (size_t)Bb * Ss * Ff * 2;
  const int xpre = (ws_size >= need_xpre) ? 1 : 0;

  init_kernel<<<1024, 256, 0, stream>>>(x, hbuf, flags, xb, xpre);

  void* args[] = {(void*)&x,  (void*)&xb, (void*)&Wf, (void*)&Uf,
                  (void*)&bf, (void*)&Wb, (void*)&Ub, (void*)&bb,
                  (void*)&out, (void*)&hbuf, (void*)&flags};
  hipError_t err;
  if (xpre) {
    err = hipLaunchCooperativeKernel((void*)bilstm_kernel<1>, dim3(2 * NWGD),
                                     dim3(256), args, 0, stream);
  } else {
    err = hipLaunchCooperativeKernel((void*)bilstm_kernel<0>, dim3(2 * NWGD),
                                     dim3(256), args, 0, stream);
  }
  if (err != hipSuccess) {
    // fallback: plain launch; 128 WGs at 1 WG/CU are fully co-resident on
    // 256 CUs, and the barrier is monotone flags.
    if (xpre) {
      bilstm_kernel<1><<<dim3(2 * NWGD), dim3(256), 0, stream>>>(
          x, xb, Wf, Uf, bf, Wb, Ub, bb, out, hbuf, flags);
    } else {
      bilstm_kernel<0><<<dim3(2 * NWGD), dim3(256), 0, stream>>>(
          x, xb, Wf, Uf, bf, Wb, Ub, bb, out, hbuf, flags);
    }
  }
}